// Round 1
// baseline (744.550 us; speedup 1.0000x reference)
//
#include <hip/hip_runtime.h>

// Sizes fixed by the problem.
#define TT 1653          // T
#define DD 512           // D
#define BB 2             // B
#define EE 8             // E heads
#define DE 64            // D/E
#define BEH 16           // B*E
#define TTILES 26        // ceil(T/64)

// ---------------------------------------------------------------------------
// Kernel 1: projections Q/K/V in [B, D, T] layout (i.e. proj(x) transposed),
// with learnable-sigmoid applied to Q and K.
//   Y[b,d,t] = sum_k W[d,k] * X[b,t,k] + bias[d]
// The [B,D,T] flat buffer reinterpreted per-head as [T,64] exactly reproduces
// the reference's transpose(0,2,1).reshape(BE,T,D_E) scrambling.
// ---------------------------------------------------------------------------
__global__ __launch_bounds__(256) void proj_kernel(
    const float* __restrict__ X,
    const float* __restrict__ W0, const float* __restrict__ b0,
    const float* __restrict__ W1, const float* __restrict__ b1,
    const float* __restrict__ W2, const float* __restrict__ b2,
    float* __restrict__ Y0, float* __restrict__ Y1, float* __restrict__ Y2)
{
    __shared__ float Ws[16][68];  // [k][d], stride 68 floats = 272B (16B mult)
    __shared__ float Xs[16][68];  // [k][t]

    const int tt = blockIdx.x;
    const int dt = blockIdx.y;
    const int z  = blockIdx.z;
    const int b = z / 3, which = z % 3;
    const float* W    = (which == 0) ? W0 : (which == 1) ? W1 : W2;
    const float* bias = (which == 0) ? b0 : (which == 1) ? b1 : b2;
    float* Y          = (which == 0) ? Y0 : (which == 1) ? Y1 : Y2;

    const int t0 = tt * 64, d0 = dt * 64;
    const float* Xb = X + (size_t)b * TT * DD;

    const int tid = threadIdx.x;
    const int tx = tid & 15, ty = tid >> 4;
    const int lrow = tid >> 2, lq = tid & 3;
    const int trow = t0 + lrow;

    float acc[4][4] = {};

    for (int k0 = 0; k0 < DD; k0 += 16) {
        float4 wv = *(const float4*)(W + (size_t)(d0 + lrow) * DD + k0 + lq * 4);
        float4 xv = make_float4(0.f, 0.f, 0.f, 0.f);
        if (trow < TT)
            xv = *(const float4*)(Xb + (size_t)trow * DD + k0 + lq * 4);
        __syncthreads();
        Ws[lq*4+0][lrow] = wv.x; Ws[lq*4+1][lrow] = wv.y;
        Ws[lq*4+2][lrow] = wv.z; Ws[lq*4+3][lrow] = wv.w;
        Xs[lq*4+0][lrow] = xv.x; Xs[lq*4+1][lrow] = xv.y;
        Xs[lq*4+2][lrow] = xv.z; Xs[lq*4+3][lrow] = xv.w;
        __syncthreads();
        #pragma unroll
        for (int k = 0; k < 16; ++k) {
            float4 a4 = *(const float4*)(&Ws[k][ty*4]);
            float4 c4 = *(const float4*)(&Xs[k][tx*4]);
            float a[4] = {a4.x, a4.y, a4.z, a4.w};
            float c[4] = {c4.x, c4.y, c4.z, c4.w};
            #pragma unroll
            for (int i = 0; i < 4; ++i)
                #pragma unroll
                for (int j = 0; j < 4; ++j)
                    acc[i][j] = fmaf(a[i], c[j], acc[i][j]);
        }
        __syncthreads();
    }

    #pragma unroll
    for (int i = 0; i < 4; ++i) {
        const int d = d0 + ty*4 + i;
        const float bb = bias[d];
        float* yrow = Y + ((size_t)b * DD + d) * TT;
        #pragma unroll
        for (int j = 0; j < 4; ++j) {
            const int t = t0 + tx*4 + j;
            if (t < TT) {
                float v = acc[i][j] + bb;
                if (which < 2) v = 1.2f / (1.0f + __expf(-1.6f * v));  // learnable sigmoid
                yrow[t] = v;   // scalar: t-stride 1653 is odd, rows misaligned for float4
            }
        }
    }
}

// ---------------------------------------------------------------------------
// Kernel 2: per head  M = O^T @ V,  M[s,d] = sum_j O[j,s] * V[j,d]
// O = att_orth[be] is [T,T]; V_h is the scrambled [T,64] reinterpret.
// One block = 64 s-rows x all 64 d.  O is read exactly once (175 MB total).
// ---------------------------------------------------------------------------
__global__ __launch_bounds__(256) void ovt_kernel(
    const float* __restrict__ orth, const float* __restrict__ Vbuf,
    float* __restrict__ Mbuf)
{
    __shared__ float Os[16][68];  // [j][s]
    __shared__ float Vs[16][68];  // [j][d]

    const int st = blockIdx.x, be = blockIdx.y;
    const int s0 = st * 64;
    const float* O  = orth + (size_t)be * TT * TT;
    const float* Vh = Vbuf + (size_t)be * DE * TT;   // [T,64] reinterpret
    float* Mh = Mbuf + (size_t)be * TT * DE;

    const int tid = threadIdx.x;
    const int tx = tid & 15, ty = tid >> 4;
    const int jr = tid >> 4;         // 0..15 row within j-step
    const int c0 = (tid & 15) * 4;   // col group

    float acc[4][4] = {};

    for (int j0 = 0; j0 < TT; j0 += 16) {
        const int j = j0 + jr;
        float o[4] = {0.f, 0.f, 0.f, 0.f};
        float4 vv = make_float4(0.f, 0.f, 0.f, 0.f);
        if (j < TT) {
            const float* orow = O + (size_t)j * TT + s0;
            #pragma unroll
            for (int u = 0; u < 4; ++u)
                if (s0 + c0 + u < TT) o[u] = orow[c0 + u];  // scalar: row stride odd
            vv = *(const float4*)(Vh + (size_t)j * DE + c0);
        }
        __syncthreads();
        Os[jr][c0+0] = o[0]; Os[jr][c0+1] = o[1];
        Os[jr][c0+2] = o[2]; Os[jr][c0+3] = o[3];
        Vs[jr][c0+0] = vv.x; Vs[jr][c0+1] = vv.y;
        Vs[jr][c0+2] = vv.z; Vs[jr][c0+3] = vv.w;
        __syncthreads();
        #pragma unroll
        for (int k = 0; k < 16; ++k) {
            float4 a4 = *(const float4*)(&Os[k][ty*4]);
            float4 c4 = *(const float4*)(&Vs[k][tx*4]);
            float a[4] = {a4.x, a4.y, a4.z, a4.w};
            float c[4] = {c4.x, c4.y, c4.z, c4.w};
            #pragma unroll
            for (int i = 0; i < 4; ++i)
                #pragma unroll
                for (int jj = 0; jj < 4; ++jj)
                    acc[i][jj] = fmaf(a[i], c[jj], acc[i][jj]);
        }
        __syncthreads();
    }

    #pragma unroll
    for (int i = 0; i < 4; ++i) {
        const int s = s0 + ty*4 + i;
        if (s < TT) {
            float4 v = make_float4(acc[i][0], acc[i][1], acc[i][2], acc[i][3]);
            *(float4*)(Mh + (size_t)s * DE + tx*4) = v;
        }
    }
}

// ---------------------------------------------------------------------------
// Kernel 3: fused attention:  out[i,d] = sum_s (q_i.k_s/sqrt(T) * P[i,s]) * M[s,d]
// Never materializes the TxT matrices. Writes directly into combined [B,T,D]
// layout (the output-side reshape is the natural head merge).
// LDS: 4 x 64x64 fp32 tiles = exactly 64 KB -> 2 blocks/CU.
// All tiles stored K-major ([k][*]) so inner reads are contiguous (2-way max).
// ---------------------------------------------------------------------------
__global__ __launch_bounds__(256) void attn_kernel(
    const float* __restrict__ Qbuf, const float* __restrict__ Kbuf,
    const float* __restrict__ Mbuf, const float* __restrict__ P,
    float* __restrict__ Hbuf)
{
    __shared__ float Qs[64][64];   // [k][i]
    __shared__ float Ks[64][64];   // [k][s]
    __shared__ float Ms[64][64];   // [s][d]
    __shared__ float Wt[64][64];   // [s][i]  (w transposed)

    const int it = blockIdx.x, be = blockIdx.y;
    const int b = be >> 3, e = be & 7;
    const int i0 = it * 64;
    const float* Qh = Qbuf + (size_t)be * DE * TT;
    const float* Kh = Kbuf + (size_t)be * DE * TT;
    const float* Mh = Mbuf + (size_t)be * TT * DE;

    const int tid = threadIdx.x;
    const int tx = tid & 15, ty = tid >> 4;
    const int lrow = tid >> 2, lq = tid & 3;

    const float inv_sqrt_T = 1.0f / sqrtf((float)TT);

    // Load Q tile once, transposed into [k][i].
    {
        const int gi = i0 + lrow;
        #pragma unroll
        for (int u = 0; u < 4; ++u) {
            float4 v = make_float4(0.f, 0.f, 0.f, 0.f);
            if (gi < TT) v = *(const float4*)(Qh + (size_t)gi * DE + lq*16 + u*4);
            const int kc = lq*16 + u*4;
            Qs[kc+0][lrow] = v.x; Qs[kc+1][lrow] = v.y;
            Qs[kc+2][lrow] = v.z; Qs[kc+3][lrow] = v.w;
        }
    }

    float out[4][4] = {};

    for (int s0 = 0; s0 < TT; s0 += 64) {
        // Load K (transposed [k][s]) and M (natural [s][d]) tiles.
        {
            const int gs = s0 + lrow;
            #pragma unroll
            for (int u = 0; u < 4; ++u) {
                float4 kv = make_float4(0.f, 0.f, 0.f, 0.f);
                float4 mv = make_float4(0.f, 0.f, 0.f, 0.f);
                if (gs < TT) {
                    kv = *(const float4*)(Kh + (size_t)gs * DE + lq*16 + u*4);
                    mv = *(const float4*)(Mh + (size_t)gs * DE + lq*16 + u*4);
                }
                const int kc = lq*16 + u*4;
                Ks[kc+0][lrow] = kv.x; Ks[kc+1][lrow] = kv.y;
                Ks[kc+2][lrow] = kv.z; Ks[kc+3][lrow] = kv.w;
                *(float4*)(&Ms[lrow][kc]) = mv;
            }
        }
        __syncthreads();   // also covers the one-time Q store on iter 0

        // w = Q @ K^T  (64x64x64)
        float w[4][4] = {};
        #pragma unroll 16
        for (int k = 0; k < 64; ++k) {
            float4 a4 = *(const float4*)(&Qs[k][ty*4]);
            float4 c4 = *(const float4*)(&Ks[k][tx*4]);
            float a[4] = {a4.x, a4.y, a4.z, a4.w};
            float c[4] = {c4.x, c4.y, c4.z, c4.w};
            #pragma unroll
            for (int i = 0; i < 4; ++i)
                #pragma unroll
                for (int j = 0; j < 4; ++j)
                    w[i][j] = fmaf(a[i], c[j], w[i][j]);
        }

        // scale by 1/sqrt(T), elementwise punish, stash transposed for pass 2.
        #pragma unroll
        for (int i = 0; i < 4; ++i) {
            const int gi = i0 + ty*4 + i;
            #pragma unroll
            for (int j = 0; j < 4; ++j) {
                const int gs = s0 + tx*4 + j;
                float p = 0.f;
                if (gi < TT && gs < TT) p = P[(size_t)gi * TT + gs];
                Wt[tx*4+j][ty*4+i] = w[i][j] * inv_sqrt_T * p;
            }
        }
        __syncthreads();

        // out += w @ M  (64x64x64)
        #pragma unroll 16
        for (int k = 0; k < 64; ++k) {
            float4 a4 = *(const float4*)(&Wt[k][ty*4]);
            float4 c4 = *(const float4*)(&Ms[k][tx*4]);
            float a[4] = {a4.x, a4.y, a4.z, a4.w};
            float c[4] = {c4.x, c4.y, c4.z, c4.w};
            #pragma unroll
            for (int i = 0; i < 4; ++i)
                #pragma unroll
                for (int j = 0; j < 4; ++j)
                    out[i][j] = fmaf(a[i], c[j], out[i][j]);
        }
        __syncthreads();
    }

    // Store into combined [B,T,D] layout: H[b, i, e*64 + d]
    #pragma unroll
    for (int i = 0; i < 4; ++i) {
        const int gi = i0 + ty*4 + i;
        if (gi < TT) {
            float4 v = make_float4(out[i][0], out[i][1], out[i][2], out[i][3]);
            *(float4*)(Hbuf + ((size_t)b * TT + gi) * DD + e*64 + tx*4) = v;
        }
    }
}

// ---------------------------------------------------------------------------
// Kernel 4: final projection  out[b,t,n] = sum_d H[b,t,d] * Wo[n,d] + bo[n]
// ---------------------------------------------------------------------------
__global__ __launch_bounds__(256) void oproj_kernel(
    const float* __restrict__ H, const float* __restrict__ Wo,
    const float* __restrict__ bo, float* __restrict__ out)
{
    __shared__ float Hs[16][68];  // [k][t]
    __shared__ float Ns[16][68];  // [k][n]

    const int tt = blockIdx.x, nt = blockIdx.y, b = blockIdx.z;
    const int t0 = tt * 64, n0 = nt * 64;
    const float* Hb = H + (size_t)b * TT * DD;

    const int tid = threadIdx.x;
    const int tx = tid & 15, ty = tid >> 4;
    const int lrow = tid >> 2, lq = tid & 3;
    const int trow = t0 + lrow;

    float acc[4][4] = {};

    for (int k0 = 0; k0 < DD; k0 += 16) {
        float4 hv = make_float4(0.f, 0.f, 0.f, 0.f);
        if (trow < TT)
            hv = *(const float4*)(Hb + (size_t)trow * DD + k0 + lq*4);
        float4 wv = *(const float4*)(Wo + (size_t)(n0 + lrow) * DD + k0 + lq*4);
        __syncthreads();
        Hs[lq*4+0][lrow] = hv.x; Hs[lq*4+1][lrow] = hv.y;
        Hs[lq*4+2][lrow] = hv.z; Hs[lq*4+3][lrow] = hv.w;
        Ns[lq*4+0][lrow] = wv.x; Ns[lq*4+1][lrow] = wv.y;
        Ns[lq*4+2][lrow] = wv.z; Ns[lq*4+3][lrow] = wv.w;
        __syncthreads();
        #pragma unroll
        for (int k = 0; k < 16; ++k) {
            float4 a4 = *(const float4*)(&Hs[k][ty*4]);
            float4 c4 = *(const float4*)(&Ns[k][tx*4]);
            float a[4] = {a4.x, a4.y, a4.z, a4.w};
            float c[4] = {c4.x, c4.y, c4.z, c4.w};
            #pragma unroll
            for (int i = 0; i < 4; ++i)
                #pragma unroll
                for (int j = 0; j < 4; ++j)
                    acc[i][j] = fmaf(a[i], c[j], acc[i][j]);
        }
        __syncthreads();
    }

    #pragma unroll
    for (int i = 0; i < 4; ++i) {
        const int t = t0 + ty*4 + i;
        if (t < TT) {
            float4 v;
            v.x = acc[i][0] + bo[n0 + tx*4 + 0];
            v.y = acc[i][1] + bo[n0 + tx*4 + 1];
            v.z = acc[i][2] + bo[n0 + tx*4 + 2];
            v.w = acc[i][3] + bo[n0 + tx*4 + 3];
            *(float4*)(out + ((size_t)b * TT + t) * DD + n0 + tx*4) = v;
        }
    }
}

// ---------------------------------------------------------------------------
extern "C" void kernel_launch(void* const* d_in, const int* in_sizes, int n_in,
                              void* d_out, int out_size, void* d_ws, size_t ws_size,
                              hipStream_t stream)
{
    (void)in_sizes; (void)n_in; (void)out_size; (void)ws_size;

    const float* X    = (const float*)d_in[0];
    const float* Wq   = (const float*)d_in[1];
    const float* bq   = (const float*)d_in[2];
    const float* Wk   = (const float*)d_in[3];
    const float* bk   = (const float*)d_in[4];
    const float* Wv   = (const float*)d_in[5];
    const float* bv   = (const float*)d_in[6];
    const float* Wo   = (const float*)d_in[7];
    const float* bo   = (const float*)d_in[8];
    const float* P    = (const float*)d_in[9];
    const float* orth = (const float*)d_in[10];
    float* out = (float*)d_out;

    // Workspace layout (fp32): 5 buffers of B*D*T = 1,692,672 floats each
    // (Q, K, V in [B,D,T]; M in [BE,T,64]; H in [B,T,D]) = 33.9 MB total.
    float* ws = (float*)d_ws;
    const size_t SZ = (size_t)BB * DD * TT;
    float* Qbuf = ws;
    float* Kbuf = ws + SZ;
    float* Vbuf = ws + 2 * SZ;
    float* Mbuf = ws + 3 * SZ;
    float* Hbuf = ws + 4 * SZ;

    dim3 blk(256);

    dim3 g1(TTILES, DD / 64, BB * 3);
    proj_kernel<<<g1, blk, 0, stream>>>(X, Wq, bq, Wk, bk, Wv, bv, Qbuf, Kbuf, Vbuf);

    dim3 g2(TTILES, BEH);
    ovt_kernel<<<g2, blk, 0, stream>>>(orth, Vbuf, Mbuf);

    dim3 g3(TTILES, BEH);
    attn_kernel<<<g3, blk, 0, stream>>>(Qbuf, Kbuf, Mbuf, P, Hbuf);

    dim3 g4(TTILES, DD / 64, BB);
    oproj_kernel<<<g4, blk, 0, stream>>>(Hbuf, Wo, bo, out);
}

// Round 2
// 602.057 us; speedup vs baseline: 1.2367x; 1.2367x over previous
//
#include <hip/hip_runtime.h>

// Sizes fixed by the problem.
#define TT 1653          // T
#define DD 512           // D
#define BB 2             // B
#define DE 64            // D/E
#define BEH 16           // B*E
#define TTILES 26        // ceil(T/64)
#define TPAD 1664        // T padded to multiple of 64 (for bf16/f32 padded rows)

typedef __attribute__((ext_vector_type(8))) short bf16x8;   // 8 bf16 in 4 VGPRs
typedef __attribute__((ext_vector_type(4))) float f32x4;

__device__ __forceinline__ short f2bf(float f) {
    union { float f; unsigned u; } v; v.f = f;
    unsigned r = v.u + 0x7fffu + ((v.u >> 16) & 1u);   // RNE
    return (short)(r >> 16);
}

// ---------------------------------------------------------------------------
// Kernel 0: copy punish matrix into an fp32 [T][TPAD] buffer, zero pad cols.
// ---------------------------------------------------------------------------
__global__ __launch_bounds__(256) void convp_kernel(
    const float* __restrict__ P, float* __restrict__ Pb)
{
    int idx = blockIdx.x * 256 + threadIdx.x;
    if (idx < TT * TPAD) {
        int r = idx / TPAD, c = idx - r * TPAD;
        Pb[idx] = (c < TT) ? P[(size_t)r * TT + c] : 0.f;
    }
}

// ---------------------------------------------------------------------------
// Kernel 1: projections Q/K/V in [B, D, T] scramble layout, stored bf16.
// sigmoid applied to Q and K. (Known-good fp32 SGEMM from round 1, bf16 out.)
// ---------------------------------------------------------------------------
__global__ __launch_bounds__(256) void proj_kernel(
    const float* __restrict__ X,
    const float* __restrict__ W0, const float* __restrict__ b0,
    const float* __restrict__ W1, const float* __restrict__ b1,
    const float* __restrict__ W2, const float* __restrict__ b2,
    short* __restrict__ Y0, short* __restrict__ Y1, short* __restrict__ Y2)
{
    __shared__ float Ws[16][68];
    __shared__ float Xs[16][68];

    const int tt = blockIdx.x;
    const int dt = blockIdx.y;
    const int z  = blockIdx.z;
    const int b = z / 3, which = z % 3;
    const float* W    = (which == 0) ? W0 : (which == 1) ? W1 : W2;
    const float* bias = (which == 0) ? b0 : (which == 1) ? b1 : b2;
    short* Y          = (which == 0) ? Y0 : (which == 1) ? Y1 : Y2;

    const int t0 = tt * 64, d0 = dt * 64;
    const float* Xb = X + (size_t)b * TT * DD;

    const int tid = threadIdx.x;
    const int tx = tid & 15, ty = tid >> 4;
    const int lrow = tid >> 2, lq = tid & 3;
    const int trow = t0 + lrow;

    float acc[4][4] = {};

    for (int k0 = 0; k0 < DD; k0 += 16) {
        float4 wv = *(const float4*)(W + (size_t)(d0 + lrow) * DD + k0 + lq * 4);
        float4 xv = make_float4(0.f, 0.f, 0.f, 0.f);
        if (trow < TT)
            xv = *(const float4*)(Xb + (size_t)trow * DD + k0 + lq * 4);
        __syncthreads();
        Ws[lq*4+0][lrow] = wv.x; Ws[lq*4+1][lrow] = wv.y;
        Ws[lq*4+2][lrow] = wv.z; Ws[lq*4+3][lrow] = wv.w;
        Xs[lq*4+0][lrow] = xv.x; Xs[lq*4+1][lrow] = xv.y;
        Xs[lq*4+2][lrow] = xv.z; Xs[lq*4+3][lrow] = xv.w;
        __syncthreads();
        #pragma unroll
        for (int k = 0; k < 16; ++k) {
            float4 a4 = *(const float4*)(&Ws[k][ty*4]);
            float4 c4 = *(const float4*)(&Xs[k][tx*4]);
            float a[4] = {a4.x, a4.y, a4.z, a4.w};
            float c[4] = {c4.x, c4.y, c4.z, c4.w};
            #pragma unroll
            for (int i = 0; i < 4; ++i)
                #pragma unroll
                for (int j = 0; j < 4; ++j)
                    acc[i][j] = fmaf(a[i], c[j], acc[i][j]);
        }
        __syncthreads();
    }

    #pragma unroll
    for (int i = 0; i < 4; ++i) {
        const int d = d0 + ty*4 + i;
        const float bb = bias[d];
        short* yrow = Y + ((size_t)b * DD + d) * TT;
        #pragma unroll
        for (int j = 0; j < 4; ++j) {
            const int t = t0 + tx*4 + j;
            if (t < TT) {
                float v = acc[i][j] + bb;
                if (which < 2) v = 1.2f / (1.0f + __expf(-1.6f * v));
                yrow[t] = f2bf(v);
            }
        }
    }
}

// ---------------------------------------------------------------------------
// Kernel 2 (MFMA): per head  Mt[d][s] = sum_j V[j][d] * O[j][s]   (= (O^T V)^T)
// O read exactly once (175 MB, HBM-bound). Output bf16 [BE][64][TPAD],
// zero-filled in the s>=T pad columns.
// ---------------------------------------------------------------------------
__global__ __launch_bounds__(256) void ovt_kernel(
    const float* __restrict__ orth, const short* __restrict__ Vb,
    short* __restrict__ Mt)
{
    __shared__ short Os[64][72];  // [s][j]
    __shared__ short Vs[64][72];  // [d][j]

    const int st = blockIdx.x, be = blockIdx.y;
    const int s0 = st * 64;
    const float* O  = orth + (size_t)be * TT * TT;
    const short* Vh = Vb + (size_t)be * DE * TT;   // flat head block, read as [j][64]
    short* Mh = Mt + (size_t)be * DE * TPAD;

    const int tid  = threadIdx.x;
    const int wave = tid >> 6, lane = tid & 63;
    const int quad = lane >> 4, l16 = lane & 15;

    f32x4 acc[4];
    #pragma unroll
    for (int i = 0; i < 4; ++i) acc[i] = (f32x4){0.f, 0.f, 0.f, 0.f};

    const int sg = s0 + lane;   // this lane's global s column for O staging

    for (int j0 = 0; j0 < TT; j0 += 64) {
        // ---- stage: transpose O chunk [64j x 64s] -> Os[s][j] (bf16),
        //             transpose V chunk [64j x 64d] -> Vs[d][j] (bf16).
        #pragma unroll
        for (int u = 0; u < 8; ++u) {
            const int jb = wave * 16 + 2 * u;
            const int j  = j0 + jb;
            float o0 = 0.f, o1 = 0.f;
            if (sg < TT) {
                if (j     < TT) o0 = O[(size_t)j * TT + sg];
                if (j + 1 < TT) o1 = O[(size_t)(j + 1) * TT + sg];
            }
            unsigned po = (unsigned)(unsigned short)f2bf(o0)
                        | ((unsigned)(unsigned short)f2bf(o1) << 16);
            *(unsigned*)&Os[lane][jb] = po;

            short v0 = 0, v1 = 0;
            if (j     < TT) v0 = Vh[(size_t)j * DE + lane];
            if (j + 1 < TT) v1 = Vh[(size_t)(j + 1) * DE + lane];
            unsigned pv = (unsigned)(unsigned short)v0
                        | ((unsigned)(unsigned short)v1 << 16);
            *(unsigned*)&Vs[lane][jb] = pv;
        }
        __syncthreads();

        // ---- MFMA: wave owns d-strip [wave*16, wave*16+16), all 64 s.
        #pragma unroll
        for (int ks = 0; ks < 2; ++ks) {
            bf16x8 a = *(const bf16x8*)&Vs[wave * 16 + l16][ks * 32 + quad * 8];
            #pragma unroll
            for (int stile = 0; stile < 4; ++stile) {
                bf16x8 bb = *(const bf16x8*)&Os[stile * 16 + l16][ks * 32 + quad * 8];
                acc[stile] = __builtin_amdgcn_mfma_f32_16x16x32_bf16(a, bb, acc[stile], 0, 0, 0);
            }
        }
        __syncthreads();
    }

    // ---- epilogue: Mt[d][s0+s] bf16; zero for s >= T (pad correctness).
    #pragma unroll
    for (int stile = 0; stile < 4; ++stile) {
        const int s = s0 + stile * 16 + l16;
        #pragma unroll
        for (int r = 0; r < 4; ++r) {
            const int d = wave * 16 + quad * 4 + r;
            float v = (s < TT) ? acc[stile][r] : 0.f;
            Mh[(size_t)d * TPAD + s] = f2bf(v);
        }
    }
}

// ---------------------------------------------------------------------------
// Kernel 3 (MFMA): fused attention.
//   out[i][d] = sum_s ( (Q K^T)[i][s] / sqrt(T) * P[i][s] ) * M[s][d]
// QK^T via MFMA -> punish in C-layout (fp32 P) -> bf16 LDS round-trip
// (the verified flash pattern) -> MFMA against Mt[d][s].
// LDS = 4*9216 + 17408 = 54272 B -> 3 blocks/CU.
// ---------------------------------------------------------------------------
__global__ __launch_bounds__(256) void attn_kernel(
    const short* __restrict__ Qb, const short* __restrict__ Kb,
    const short* __restrict__ Mt, const float* __restrict__ Pb,
    float* __restrict__ Hbuf)
{
    __shared__ short Qs[64][72];  // [i][d]
    __shared__ short Ks[64][72];  // [s][d]
    __shared__ short Ms[64][72];  // [d][s]
    __shared__ short Wl[64][72];  // [i][s]  (punished scores, bf16)
    __shared__ float Ps[64][68];  // [i][s]  fp32 punish tile

    const int it = blockIdx.x, be = blockIdx.y;
    const int b = be >> 3, e = be & 7;
    const int i0 = it * 64;
    const short* Qh = Qb + (size_t)be * DE * TT;
    const short* Kh = Kb + (size_t)be * DE * TT;
    const short* Mh = Mt + (size_t)be * DE * TPAD;

    const int tid  = threadIdx.x;
    const int wave = tid >> 6, lane = tid & 63;
    const int quad = lane >> 4, l16 = lane & 15;

    const float invs = 0.024598297f;  // 1/sqrt(1653)

    // staging mapping: 256 threads cover 64 rows x 64 cols (16 cols each)
    const int srow = tid >> 2, scg = (tid & 3) * 16;

    // ---- stage Q tile once: Qs[i][d]
    {
        const int gi = i0 + srow;
        uint4 z = make_uint4(0u, 0u, 0u, 0u);
        uint4 v0 = z, v1 = z;
        if (gi < TT) {
            v0 = *(const uint4*)(Qh + (size_t)gi * DE + scg);
            v1 = *(const uint4*)(Qh + (size_t)gi * DE + scg + 8);
        }
        *(uint4*)&Qs[srow][scg]     = v0;
        *(uint4*)&Qs[srow][scg + 8] = v1;
    }

    f32x4 out[4];
    #pragma unroll
    for (int i = 0; i < 4; ++i) out[i] = (f32x4){0.f, 0.f, 0.f, 0.f};

    for (int s0 = 0; s0 < TT; s0 += 64) {
        // ---- stage K [s][d], M [d][s], P [i][s]
        {
            const int gs = s0 + srow;
            uint4 z = make_uint4(0u, 0u, 0u, 0u);
            uint4 k0 = z, k1 = z;
            if (gs < TT) {
                k0 = *(const uint4*)(Kh + (size_t)gs * DE + scg);
                k1 = *(const uint4*)(Kh + (size_t)gs * DE + scg + 8);
            }
            *(uint4*)&Ks[srow][scg]     = k0;
            *(uint4*)&Ks[srow][scg + 8] = k1;

            // M: row = d (always valid), cols s0+scg.. (padded buffer, zero-filled)
            uint4 m0 = *(const uint4*)(Mh + (size_t)srow * TPAD + s0 + scg);
            uint4 m1 = *(const uint4*)(Mh + (size_t)srow * TPAD + s0 + scg + 8);
            *(uint4*)&Ms[srow][scg]     = m0;
            *(uint4*)&Ms[srow][scg + 8] = m1;

            // P: fp32, row gi guard
            const int gi = i0 + srow;
            float4 fz = make_float4(0.f, 0.f, 0.f, 0.f);
            float4 p0 = fz, p1 = fz, p2 = fz, p3 = fz;
            if (gi < TT) {
                const float* prow = Pb + (size_t)gi * TPAD + s0 + scg;
                p0 = *(const float4*)(prow + 0);
                p1 = *(const float4*)(prow + 4);
                p2 = *(const float4*)(prow + 8);
                p3 = *(const float4*)(prow + 12);
            }
            *(float4*)&Ps[srow][scg + 0]  = p0;
            *(float4*)&Ps[srow][scg + 4]  = p1;
            *(float4*)&Ps[srow][scg + 8]  = p2;
            *(float4*)&Ps[srow][scg + 12] = p3;
        }
        __syncthreads();

        // ---- mm1: w = Q K^T (wave strip: i in [wave*16, wave*16+16), all 64 s)
        f32x4 w[4];
        #pragma unroll
        for (int i = 0; i < 4; ++i) w[i] = (f32x4){0.f, 0.f, 0.f, 0.f};
        #pragma unroll
        for (int ks = 0; ks < 2; ++ks) {
            bf16x8 a = *(const bf16x8*)&Qs[wave * 16 + l16][ks * 32 + quad * 8];
            #pragma unroll
            for (int stile = 0; stile < 4; ++stile) {
                bf16x8 bb = *(const bf16x8*)&Ks[stile * 16 + l16][ks * 32 + quad * 8];
                w[stile] = __builtin_amdgcn_mfma_f32_16x16x32_bf16(a, bb, w[stile], 0, 0, 0);
            }
        }

        // ---- punish + bf16 round-trip into Wl[i][s] (wave-private rows)
        #pragma unroll
        for (int stile = 0; stile < 4; ++stile) {
            const int sl = stile * 16 + l16;
            #pragma unroll
            for (int r = 0; r < 4; ++r) {
                const int il = wave * 16 + quad * 4 + r;
                float v = w[stile][r] * invs * Ps[il][sl];
                Wl[il][sl] = f2bf(v);
            }
        }
        // no barrier needed: each wave reads only its own Wl rows below.

        // ---- mm2: out += Wl @ M   (B from Ms[d][s])
        #pragma unroll
        for (int ks = 0; ks < 2; ++ks) {
            bf16x8 a = *(const bf16x8*)&Wl[wave * 16 + l16][ks * 32 + quad * 8];
            #pragma unroll
            for (int dt = 0; dt < 4; ++dt) {
                bf16x8 bb = *(const bf16x8*)&Ms[dt * 16 + l16][ks * 32 + quad * 8];
                out[dt] = __builtin_amdgcn_mfma_f32_16x16x32_bf16(a, bb, out[dt], 0, 0, 0);
            }
        }
        __syncthreads();   // protect Ks/Ms/Ps before next stage
    }

    // ---- epilogue: H[b][i][e*64+d] fp32 (natural head-merge layout)
    #pragma unroll
    for (int dt = 0; dt < 4; ++dt) {
        const int d = dt * 16 + l16;
        #pragma unroll
        for (int r = 0; r < 4; ++r) {
            const int gi = i0 + wave * 16 + quad * 4 + r;
            if (gi < TT)
                Hbuf[((size_t)b * TT + gi) * DD + e * 64 + d] = out[dt][r];
        }
    }
}

// ---------------------------------------------------------------------------
// Kernel 4: final projection (unchanged fp32 SGEMM from round 1)
// ---------------------------------------------------------------------------
__global__ __launch_bounds__(256) void oproj_kernel(
    const float* __restrict__ H, const float* __restrict__ Wo,
    const float* __restrict__ bo, float* __restrict__ out)
{
    __shared__ float Hs[16][68];
    __shared__ float Ns[16][68];

    const int tt = blockIdx.x, nt = blockIdx.y, b = blockIdx.z;
    const int t0 = tt * 64, n0 = nt * 64;
    const float* Hb = H + (size_t)b * TT * DD;

    const int tid = threadIdx.x;
    const int tx = tid & 15, ty = tid >> 4;
    const int lrow = tid >> 2, lq = tid & 3;
    const int trow = t0 + lrow;

    float acc[4][4] = {};

    for (int k0 = 0; k0 < DD; k0 += 16) {
        float4 hv = make_float4(0.f, 0.f, 0.f, 0.f);
        if (trow < TT)
            hv = *(const float4*)(Hb + (size_t)trow * DD + k0 + lq*4);
        float4 wv = *(const float4*)(Wo + (size_t)(n0 + lrow) * DD + k0 + lq*4);
        __syncthreads();
        Hs[lq*4+0][lrow] = hv.x; Hs[lq*4+1][lrow] = hv.y;
        Hs[lq*4+2][lrow] = hv.z; Hs[lq*4+3][lrow] = hv.w;
        Ns[lq*4+0][lrow] = wv.x; Ns[lq*4+1][lrow] = wv.y;
        Ns[lq*4+2][lrow] = wv.z; Ns[lq*4+3][lrow] = wv.w;
        __syncthreads();
        #pragma unroll
        for (int k = 0; k < 16; ++k) {
            float4 a4 = *(const float4*)(&Hs[k][ty*4]);
            float4 c4 = *(const float4*)(&Ns[k][tx*4]);
            float a[4] = {a4.x, a4.y, a4.z, a4.w};
            float c[4] = {c4.x, c4.y, c4.z, c4.w};
            #pragma unroll
            for (int i = 0; i < 4; ++i)
                #pragma unroll
                for (int j = 0; j < 4; ++j)
                    acc[i][j] = fmaf(a[i], c[j], acc[i][j]);
        }
        __syncthreads();
    }

    #pragma unroll
    for (int i = 0; i < 4; ++i) {
        const int t = t0 + ty*4 + i;
        if (t < TT) {
            float4 v;
            v.x = acc[i][0] + bo[n0 + tx*4 + 0];
            v.y = acc[i][1] + bo[n0 + tx*4 + 1];
            v.z = acc[i][2] + bo[n0 + tx*4 + 2];
            v.w = acc[i][3] + bo[n0 + tx*4 + 3];
            *(float4*)(out + ((size_t)b * TT + t) * DD + n0 + tx*4) = v;
        }
    }
}

// ---------------------------------------------------------------------------
extern "C" void kernel_launch(void* const* d_in, const int* in_sizes, int n_in,
                              void* d_out, int out_size, void* d_ws, size_t ws_size,
                              hipStream_t stream)
{
    (void)in_sizes; (void)n_in; (void)out_size; (void)ws_size;

    const float* X    = (const float*)d_in[0];
    const float* Wq   = (const float*)d_in[1];
    const float* bq   = (const float*)d_in[2];
    const float* Wk   = (const float*)d_in[3];
    const float* bk   = (const float*)d_in[4];
    const float* Wv   = (const float*)d_in[5];
    const float* bv   = (const float*)d_in[6];
    const float* Wo   = (const float*)d_in[7];
    const float* bo   = (const float*)d_in[8];
    const float* P    = (const float*)d_in[9];
    const float* orth = (const float*)d_in[10];
    float* out = (float*)d_out;

    // Workspace layout (byte offsets, all 256B-aligned):
    //   Qb, Kb, Vb : bf16, B*D*T each            (3,385,344 B each)
    //   Mt         : bf16, BE*64*TPAD            (3,407,872 B)
    //   Pb         : fp32, T*TPAD                (11,002,368 B)
    //   Hbuf       : fp32, B*T*D                 (6,770,688 B)   total ~29.9 MB
    char* ws = (char*)d_ws;
    const size_t SZH = (size_t)BB * DD * TT * sizeof(short);
    short* Qb = (short*)(ws);
    short* Kb = (short*)(ws + SZH);
    short* Vb = (short*)(ws + 2 * SZH);
    short* Mtb = (short*)(ws + 3 * SZH);
    float* Pb  = (float*)(ws + 3 * SZH + (size_t)BEH * DE * TPAD * sizeof(short));
    float* Hbuf = (float*)(ws + 3 * SZH + (size_t)BEH * DE * TPAD * sizeof(short)
                              + (size_t)TT * TPAD * sizeof(float));

    dim3 blk(256);

    convp_kernel<<<dim3((TT * TPAD + 255) / 256), blk, 0, stream>>>(P, Pb);

    dim3 g1(TTILES, DD / 64, BB * 3);
    proj_kernel<<<g1, blk, 0, stream>>>(X, Wq, bq, Wk, bk, Wv, bv, Qb, Kb, Vb);

    dim3 g2(TTILES, BEH);
    ovt_kernel<<<g2, blk, 0, stream>>>(orth, Vb, Mtb);

    dim3 g3(TTILES, BEH);
    attn_kernel<<<g3, blk, 0, stream>>>(Qb, Kb, Mtb, Pb, Hbuf);

    dim3 g4(TTILES, DD / 64, BB);
    oproj_kernel<<<g4, blk, 0, stream>>>(Hbuf, Wo, bo, out);
}

// Round 3
// 497.718 us; speedup vs baseline: 1.4959x; 1.2096x over previous
//
#include <hip/hip_runtime.h>

// Sizes fixed by the problem.
#define TT 1653          // T
#define DD 512           // D
#define BB 2             // B
#define DE 64            // D/E
#define BEH 16           // B*E
#define TTILES 26        // ceil(T/64)
#define TPAD 1664        // T padded to multiple of 64
#define STILE 256        // ovt2 s-tile width
#define SQN 7            // ceil(TPAD/STILE) -> covers s in [0,1792)
#define NJC 4            // ovt2 j-split
#define MPSTRIDE 1792    // Mpart row stride (floats) = SQN*STILE

typedef __attribute__((ext_vector_type(8))) short bf16x8;   // 8 bf16 in 4 VGPRs
typedef __attribute__((ext_vector_type(4))) float f32x4;
typedef float f32x4u __attribute__((ext_vector_type(4), aligned(4)));  // 4B-aligned vec load

__device__ __forceinline__ short f2bf(float f) {
    union { float f; unsigned u; } v; v.f = f;
    unsigned r = v.u + 0x7fffu + ((v.u >> 16) & 1u);   // RNE
    return (short)(r >> 16);
}
__device__ __forceinline__ unsigned pack2(float a, float b) {
    return (unsigned)(unsigned short)f2bf(a) | ((unsigned)(unsigned short)f2bf(b) << 16);
}

// ---------------------------------------------------------------------------
// Kernel 0: copy punish matrix into an fp32 [T][TPAD] buffer, zero pad cols.
// ---------------------------------------------------------------------------
__global__ __launch_bounds__(256) void convp_kernel(
    const float* __restrict__ P, float* __restrict__ Pb)
{
    int idx = blockIdx.x * 256 + threadIdx.x;
    if (idx < TT * TPAD) {
        int r = idx / TPAD, c = idx - r * TPAD;
        Pb[idx] = (c < TT) ? P[(size_t)r * TT + c] : 0.f;
    }
}

// ---------------------------------------------------------------------------
// Kernel 1: projections Q/K/V in [B, D, T] scramble layout, stored bf16.
// ---------------------------------------------------------------------------
__global__ __launch_bounds__(256) void proj_kernel(
    const float* __restrict__ X,
    const float* __restrict__ W0, const float* __restrict__ b0,
    const float* __restrict__ W1, const float* __restrict__ b1,
    const float* __restrict__ W2, const float* __restrict__ b2,
    short* __restrict__ Y0, short* __restrict__ Y1, short* __restrict__ Y2)
{
    __shared__ float Ws[16][68];
    __shared__ float Xs[16][68];

    const int tt = blockIdx.x;
    const int dt = blockIdx.y;
    const int z  = blockIdx.z;
    const int b = z / 3, which = z % 3;
    const float* W    = (which == 0) ? W0 : (which == 1) ? W1 : W2;
    const float* bias = (which == 0) ? b0 : (which == 1) ? b1 : b2;
    short* Y          = (which == 0) ? Y0 : (which == 1) ? Y1 : Y2;

    const int t0 = tt * 64, d0 = dt * 64;
    const float* Xb = X + (size_t)b * TT * DD;

    const int tid = threadIdx.x;
    const int tx = tid & 15, ty = tid >> 4;
    const int lrow = tid >> 2, lq = tid & 3;
    const int trow = t0 + lrow;

    float acc[4][4] = {};

    for (int k0 = 0; k0 < DD; k0 += 16) {
        float4 wv = *(const float4*)(W + (size_t)(d0 + lrow) * DD + k0 + lq * 4);
        float4 xv = make_float4(0.f, 0.f, 0.f, 0.f);
        if (trow < TT)
            xv = *(const float4*)(Xb + (size_t)trow * DD + k0 + lq * 4);
        __syncthreads();
        Ws[lq*4+0][lrow] = wv.x; Ws[lq*4+1][lrow] = wv.y;
        Ws[lq*4+2][lrow] = wv.z; Ws[lq*4+3][lrow] = wv.w;
        Xs[lq*4+0][lrow] = xv.x; Xs[lq*4+1][lrow] = xv.y;
        Xs[lq*4+2][lrow] = xv.z; Xs[lq*4+3][lrow] = xv.w;
        __syncthreads();
        #pragma unroll
        for (int k = 0; k < 16; ++k) {
            float4 a4 = *(const float4*)(&Ws[k][ty*4]);
            float4 c4 = *(const float4*)(&Xs[k][tx*4]);
            float a[4] = {a4.x, a4.y, a4.z, a4.w};
            float c[4] = {c4.x, c4.y, c4.z, c4.w};
            #pragma unroll
            for (int i = 0; i < 4; ++i)
                #pragma unroll
                for (int j = 0; j < 4; ++j)
                    acc[i][j] = fmaf(a[i], c[j], acc[i][j]);
        }
        __syncthreads();
    }

    #pragma unroll
    for (int i = 0; i < 4; ++i) {
        const int d = d0 + ty*4 + i;
        const float bb = bias[d];
        short* yrow = Y + ((size_t)b * DD + d) * TT;
        #pragma unroll
        for (int j = 0; j < 4; ++j) {
            const int t = t0 + tx*4 + j;
            if (t < TT) {
                float v = acc[i][j] + bb;
                if (which < 2) v = 1.2f / (1.0f + __expf(-1.6f * v));
                yrow[t] = f2bf(v);
            }
        }
    }
}

// ---------------------------------------------------------------------------
// Kernel 2 (MFMA, restructured): partial Mt.
//   Mpart[jc][be][d][s] = sum_{j in chunk jc} V[j][d] * O[j][s]
// Block = (s-tile 256, head, j-chunk). O rows are read as full-wave float4
// sweeps: 64 lanes x 16 B = 1 KB contiguous per instruction (DRAM-friendly),
// then transposed into bf16 Os[s][j] in LDS. LDS 46 KB -> 3 blocks/CU.
// ---------------------------------------------------------------------------
__global__ __launch_bounds__(256) void ovt2_kernel(
    const float* __restrict__ orth, const short* __restrict__ Vb,
    float* __restrict__ Mpart)
{
    __shared__ short Os[STILE][72];  // [s_local][j_local] bf16, 36,864 B
    __shared__ short Vs[64][72];     // [d][j_local] bf16,     9,216 B

    const int sq = blockIdx.x, be = blockIdx.y, jc = blockIdx.z;
    const int s0 = sq * STILE;
    const int jt0 = (jc < 2) ? jc * 7 : 14 + (jc - 2) * 6;   // tiles {7,7,6,6}
    const int jtn = (jc < 2) ? 7 : 6;

    const float* O  = orth + (size_t)be * TT * TT;
    const short* Vh = Vb + (size_t)be * DE * TT;   // head block read as [j][64]

    const int tid  = threadIdx.x;
    const int wave = tid >> 6, lane = tid & 63;
    const int quad = lane >> 4, l16 = lane & 15;

    const int colbase = s0 + 4 * lane;
    const bool fullcol = (colbase + 3 <= TT - 1);

    f32x4 acc[16];
    #pragma unroll
    for (int i = 0; i < 16; ++i) acc[i] = (f32x4){0.f, 0.f, 0.f, 0.f};

    for (int t = 0; t < jtn; ++t) {
        const int j0 = (jt0 + t) * 64;

        // ---- stage: O row-pairs (1 KB contiguous per wave-load) + V rows.
        #pragma unroll
        for (int u = 0; u < 8; ++u) {
            const int jl = wave * 16 + 2 * u;   // local j (even)
            const int j  = j0 + jl;

            float o0[4] = {0.f, 0.f, 0.f, 0.f};
            float o1[4] = {0.f, 0.f, 0.f, 0.f};
            if (fullcol) {
                if (j < TT) {
                    f32x4u v = *(const f32x4u*)(O + (size_t)j * TT + colbase);
                    o0[0] = v.x; o0[1] = v.y; o0[2] = v.z; o0[3] = v.w;
                }
                if (j + 1 < TT) {
                    f32x4u v = *(const f32x4u*)(O + (size_t)(j + 1) * TT + colbase);
                    o1[0] = v.x; o1[1] = v.y; o1[2] = v.z; o1[3] = v.w;
                }
            } else {
                #pragma unroll
                for (int i = 0; i < 4; ++i) {
                    const int c = colbase + i;
                    if (c < TT) {
                        if (j < TT)     o0[i] = O[(size_t)j * TT + c];
                        if (j + 1 < TT) o1[i] = O[(size_t)(j + 1) * TT + c];
                    }
                }
            }
            #pragma unroll
            for (int i = 0; i < 4; ++i)
                *(unsigned*)&Os[4 * lane + i][jl] = pack2(o0[i], o1[i]);

            // V: lane = d, rows j / j+1
            short v0 = 0, v1 = 0;
            if (j < TT)     v0 = Vh[(size_t)j * DE + lane];
            if (j + 1 < TT) v1 = Vh[(size_t)(j + 1) * DE + lane];
            *(unsigned*)&Vs[lane][jl] =
                (unsigned)(unsigned short)v0 | ((unsigned)(unsigned short)v1 << 16);
        }
        __syncthreads();

        // ---- MFMA: wave owns d-strip [wave*16, wave*16+16), all 256 s.
        #pragma unroll
        for (int ks = 0; ks < 2; ++ks) {
            bf16x8 a = *(const bf16x8*)&Vs[wave * 16 + l16][ks * 32 + quad * 8];
            #pragma unroll
            for (int nt = 0; nt < 16; ++nt) {
                bf16x8 bb = *(const bf16x8*)&Os[nt * 16 + l16][ks * 32 + quad * 8];
                acc[nt] = __builtin_amdgcn_mfma_f32_16x16x32_bf16(a, bb, acc[nt], 0, 0, 0);
            }
        }
        __syncthreads();
    }

    // ---- epilogue: fp32 partial write.
    float* Mp = Mpart + (size_t)(jc * BEH + be) * DE * MPSTRIDE;
    #pragma unroll
    for (int nt = 0; nt < 16; ++nt) {
        const int s = s0 + nt * 16 + l16;
        #pragma unroll
        for (int r = 0; r < 4; ++r) {
            const int d = wave * 16 + quad * 4 + r;
            Mp[(size_t)d * MPSTRIDE + s] = acc[nt][r];
        }
    }
}

// ---------------------------------------------------------------------------
// Kernel 2b: reduce the 4 j-chunk partials -> bf16 Mt[be][d][TPAD].
// ---------------------------------------------------------------------------
__global__ __launch_bounds__(256) void mreduce_kernel(
    const float* __restrict__ Mpart, short* __restrict__ Mt)
{
    const int g = blockIdx.x * 256 + threadIdx.x;   // one per 4-s group
    const int NG = TPAD / 4;                        // 416
    if (g >= BEH * DE * NG) return;
    const int bd = g / NG;
    const int s4 = (g - bd * NG) * 4;

    const size_t jstride = (size_t)BEH * DE * MPSTRIDE;
    const float* p = Mpart + (size_t)bd * MPSTRIDE + s4;
    f32x4u a0 = *(const f32x4u*)(p);
    f32x4u a1 = *(const f32x4u*)(p + jstride);
    f32x4u a2 = *(const f32x4u*)(p + 2 * jstride);
    f32x4u a3 = *(const f32x4u*)(p + 3 * jstride);
    float s0 = a0.x + a1.x + a2.x + a3.x;
    float s1 = a0.y + a1.y + a2.y + a3.y;
    float s2 = a0.z + a1.z + a2.z + a3.z;
    float s3 = a0.w + a1.w + a2.w + a3.w;

    uint2 o;
    o.x = pack2(s0, s1);
    o.y = pack2(s2, s3);
    *(uint2*)(Mt + (size_t)bd * TPAD + s4) = o;
}

// ---------------------------------------------------------------------------
// Kernel 3 (MFMA): fused attention (unchanged from round 2).
// ---------------------------------------------------------------------------
__global__ __launch_bounds__(256) void attn_kernel(
    const short* __restrict__ Qb, const short* __restrict__ Kb,
    const short* __restrict__ Mt, const float* __restrict__ Pb,
    float* __restrict__ Hbuf)
{
    __shared__ short Qs[64][72];  // [i][d]
    __shared__ short Ks[64][72];  // [s][d]
    __shared__ short Ms[64][72];  // [d][s]
    __shared__ short Wl[64][72];  // [i][s]
    __shared__ float Ps[64][68];  // [i][s]

    const int it = blockIdx.x, be = blockIdx.y;
    const int b = be >> 3, e = be & 7;
    const int i0 = it * 64;
    const short* Qh = Qb + (size_t)be * DE * TT;
    const short* Kh = Kb + (size_t)be * DE * TT;
    const short* Mh = Mt + (size_t)be * DE * TPAD;

    const int tid  = threadIdx.x;
    const int wave = tid >> 6, lane = tid & 63;
    const int quad = lane >> 4, l16 = lane & 15;

    const float invs = 0.024598297f;  // 1/sqrt(1653)

    const int srow = tid >> 2, scg = (tid & 3) * 16;

    {
        const int gi = i0 + srow;
        uint4 z = make_uint4(0u, 0u, 0u, 0u);
        uint4 v0 = z, v1 = z;
        if (gi < TT) {
            v0 = *(const uint4*)(Qh + (size_t)gi * DE + scg);
            v1 = *(const uint4*)(Qh + (size_t)gi * DE + scg + 8);
        }
        *(uint4*)&Qs[srow][scg]     = v0;
        *(uint4*)&Qs[srow][scg + 8] = v1;
    }

    f32x4 out[4];
    #pragma unroll
    for (int i = 0; i < 4; ++i) out[i] = (f32x4){0.f, 0.f, 0.f, 0.f};

    for (int s0 = 0; s0 < TT; s0 += 64) {
        {
            const int gs = s0 + srow;
            uint4 z = make_uint4(0u, 0u, 0u, 0u);
            uint4 k0 = z, k1 = z;
            if (gs < TT) {
                k0 = *(const uint4*)(Kh + (size_t)gs * DE + scg);
                k1 = *(const uint4*)(Kh + (size_t)gs * DE + scg + 8);
            }
            *(uint4*)&Ks[srow][scg]     = k0;
            *(uint4*)&Ks[srow][scg + 8] = k1;

            uint4 m0 = *(const uint4*)(Mh + (size_t)srow * TPAD + s0 + scg);
            uint4 m1 = *(const uint4*)(Mh + (size_t)srow * TPAD + s0 + scg + 8);
            *(uint4*)&Ms[srow][scg]     = m0;
            *(uint4*)&Ms[srow][scg + 8] = m1;

            const int gi = i0 + srow;
            float4 fz = make_float4(0.f, 0.f, 0.f, 0.f);
            float4 p0 = fz, p1 = fz, p2 = fz, p3 = fz;
            if (gi < TT) {
                const float* prow = Pb + (size_t)gi * TPAD + s0 + scg;
                p0 = *(const float4*)(prow + 0);
                p1 = *(const float4*)(prow + 4);
                p2 = *(const float4*)(prow + 8);
                p3 = *(const float4*)(prow + 12);
            }
            *(float4*)&Ps[srow][scg + 0]  = p0;
            *(float4*)&Ps[srow][scg + 4]  = p1;
            *(float4*)&Ps[srow][scg + 8]  = p2;
            *(float4*)&Ps[srow][scg + 12] = p3;
        }
        __syncthreads();

        f32x4 w[4];
        #pragma unroll
        for (int i = 0; i < 4; ++i) w[i] = (f32x4){0.f, 0.f, 0.f, 0.f};
        #pragma unroll
        for (int ks = 0; ks < 2; ++ks) {
            bf16x8 a = *(const bf16x8*)&Qs[wave * 16 + l16][ks * 32 + quad * 8];
            #pragma unroll
            for (int stile = 0; stile < 4; ++stile) {
                bf16x8 bb = *(const bf16x8*)&Ks[stile * 16 + l16][ks * 32 + quad * 8];
                w[stile] = __builtin_amdgcn_mfma_f32_16x16x32_bf16(a, bb, w[stile], 0, 0, 0);
            }
        }

        #pragma unroll
        for (int stile = 0; stile < 4; ++stile) {
            const int sl = stile * 16 + l16;
            #pragma unroll
            for (int r = 0; r < 4; ++r) {
                const int il = wave * 16 + quad * 4 + r;
                float v = w[stile][r] * invs * Ps[il][sl];
                Wl[il][sl] = f2bf(v);
            }
        }

        #pragma unroll
        for (int ks = 0; ks < 2; ++ks) {
            bf16x8 a = *(const bf16x8*)&Wl[wave * 16 + l16][ks * 32 + quad * 8];
            #pragma unroll
            for (int dt = 0; dt < 4; ++dt) {
                bf16x8 bb = *(const bf16x8*)&Ms[dt * 16 + l16][ks * 32 + quad * 8];
                out[dt] = __builtin_amdgcn_mfma_f32_16x16x32_bf16(a, bb, out[dt], 0, 0, 0);
            }
        }
        __syncthreads();
    }

    #pragma unroll
    for (int dt = 0; dt < 4; ++dt) {
        const int d = dt * 16 + l16;
        #pragma unroll
        for (int r = 0; r < 4; ++r) {
            const int gi = i0 + wave * 16 + quad * 4 + r;
            if (gi < TT)
                Hbuf[((size_t)b * TT + gi) * DD + e * 64 + d] = out[dt][r];
        }
    }
}

// ---------------------------------------------------------------------------
// Kernel 4: final projection (unchanged fp32 SGEMM).
// ---------------------------------------------------------------------------
__global__ __launch_bounds__(256) void oproj_kernel(
    const float* __restrict__ H, const float* __restrict__ Wo,
    const float* __restrict__ bo, float* __restrict__ out)
{
    __shared__ float Hs[16][68];
    __shared__ float Ns[16][68];

    const int tt = blockIdx.x, nt = blockIdx.y, b = blockIdx.z;
    const int t0 = tt * 64, n0 = nt * 64;
    const float* Hb = H + (size_t)b * TT * DD;

    const int tid = threadIdx.x;
    const int tx = tid & 15, ty = tid >> 4;
    const int lrow = tid >> 2, lq = tid & 3;
    const int trow = t0 + lrow;

    float acc[4][4] = {};

    for (int k0 = 0; k0 < DD; k0 += 16) {
        float4 hv = make_float4(0.f, 0.f, 0.f, 0.f);
        if (trow < TT)
            hv = *(const float4*)(Hb + (size_t)trow * DD + k0 + lq*4);
        float4 wv = *(const float4*)(Wo + (size_t)(n0 + lrow) * DD + k0 + lq*4);
        __syncthreads();
        Hs[lq*4+0][lrow] = hv.x; Hs[lq*4+1][lrow] = hv.y;
        Hs[lq*4+2][lrow] = hv.z; Hs[lq*4+3][lrow] = hv.w;
        Ns[lq*4+0][lrow] = wv.x; Ns[lq*4+1][lrow] = wv.y;
        Ns[lq*4+2][lrow] = wv.z; Ns[lq*4+3][lrow] = wv.w;
        __syncthreads();
        #pragma unroll
        for (int k = 0; k < 16; ++k) {
            float4 a4 = *(const float4*)(&Hs[k][ty*4]);
            float4 c4 = *(const float4*)(&Ns[k][tx*4]);
            float a[4] = {a4.x, a4.y, a4.z, a4.w};
            float c[4] = {c4.x, c4.y, c4.z, c4.w};
            #pragma unroll
            for (int i = 0; i < 4; ++i)
                #pragma unroll
                for (int j = 0; j < 4; ++j)
                    acc[i][j] = fmaf(a[i], c[j], acc[i][j]);
        }
        __syncthreads();
    }

    #pragma unroll
    for (int i = 0; i < 4; ++i) {
        const int t = t0 + ty*4 + i;
        if (t < TT) {
            float4 v;
            v.x = acc[i][0] + bo[n0 + tx*4 + 0];
            v.y = acc[i][1] + bo[n0 + tx*4 + 1];
            v.z = acc[i][2] + bo[n0 + tx*4 + 2];
            v.w = acc[i][3] + bo[n0 + tx*4 + 3];
            *(float4*)(out + ((size_t)b * TT + t) * DD + n0 + tx*4) = v;
        }
    }
}

// ---------------------------------------------------------------------------
extern "C" void kernel_launch(void* const* d_in, const int* in_sizes, int n_in,
                              void* d_out, int out_size, void* d_ws, size_t ws_size,
                              hipStream_t stream)
{
    (void)in_sizes; (void)n_in; (void)out_size; (void)ws_size;

    const float* X    = (const float*)d_in[0];
    const float* Wq   = (const float*)d_in[1];
    const float* bq   = (const float*)d_in[2];
    const float* Wk   = (const float*)d_in[3];
    const float* bk   = (const float*)d_in[4];
    const float* Wv   = (const float*)d_in[5];
    const float* bv   = (const float*)d_in[6];
    const float* Wo   = (const float*)d_in[7];
    const float* bo   = (const float*)d_in[8];
    const float* P    = (const float*)d_in[9];
    const float* orth = (const float*)d_in[10];
    float* out = (float*)d_out;

    // Workspace layout:
    //   Qb/Kb/Vb bf16 [B*D*T]           3 x 3,385,344 B
    //   Mtb      bf16 [BE*64*TPAD]          3,407,872 B
    //   Pb       fp32 [T*TPAD]             11,002,368 B
    //   Mpart    fp32 [4][BE*64][1792]     29,360,128 B   (dead after mreduce)
    //   Hbuf     fp32 [B*T*D]  -- ALIASES Mpart (written by attn, after mreduce)
    // total ~54 MB
    char* ws = (char*)d_ws;
    const size_t SZH = (size_t)BB * DD * TT * sizeof(short);
    short* Qb  = (short*)(ws);
    short* Kb  = (short*)(ws + SZH);
    short* Vb  = (short*)(ws + 2 * SZH);
    short* Mtb = (short*)(ws + 3 * SZH);
    float* Pb  = (float*)(ws + 3 * SZH + (size_t)BEH * DE * TPAD * sizeof(short));
    char*  after_pb = ws + 3 * SZH + (size_t)BEH * DE * TPAD * sizeof(short)
                         + (size_t)TT * TPAD * sizeof(float);
    float* Mpart = (float*)after_pb;
    float* Hbuf  = (float*)after_pb;   // alias: Mpart dead before attn runs

    dim3 blk(256);

    convp_kernel<<<dim3((TT * TPAD + 255) / 256), blk, 0, stream>>>(P, Pb);

    dim3 g1(TTILES, DD / 64, BB * 3);
    proj_kernel<<<g1, blk, 0, stream>>>(X, Wq, bq, Wk, bk, Wv, bv, Qb, Kb, Vb);

    dim3 g2(SQN, BEH, NJC);
    ovt2_kernel<<<g2, blk, 0, stream>>>(orth, Vb, Mpart);

    dim3 gr((BEH * DE * (TPAD / 4) + 255) / 256);
    mreduce_kernel<<<gr, blk, 0, stream>>>(Mpart, Mtb);

    dim3 g3(TTILES, BEH);
    attn_kernel<<<g3, blk, 0, stream>>>(Qb, Kb, Mtb, Pb, Hbuf);

    dim3 g4(TTILES, DD / 64, BB);
    oproj_kernel<<<g4, blk, 0, stream>>>(Hbuf, Wo, bo, out);
}

// Round 4
// 424.725 us; speedup vs baseline: 1.7530x; 1.1719x over previous
//
#include <hip/hip_runtime.h>

// Sizes fixed by the problem.
#define TT 1653          // T
#define DD 512           // D
#define BB 2             // B
#define DE 64            // D/E
#define BEH 16           // B*E
#define TTILES 26        // ceil(T/64)
#define TPAD 1664        // T padded to multiple of 64
#define STILE 128        // ovt3 s-tile width
#define SQN 13           // TPAD/STILE
#define NJC 4            // ovt3 j-split
#define MPSTRIDE TPAD    // Mpart row stride (floats)

typedef __attribute__((ext_vector_type(8))) short bf16x8;   // 8 bf16 (4 VGPRs)
typedef __attribute__((ext_vector_type(4))) float f32x4;
typedef short bf16x8u __attribute__((ext_vector_type(8), aligned(4)));

__device__ __forceinline__ short f2bf(float f) {
    union { float f; unsigned u; } v; v.f = f;
    unsigned r = v.u + 0x7fffu + ((v.u >> 16) & 1u);   // RNE
    return (short)(r >> 16);
}
__device__ __forceinline__ unsigned pack2(float a, float b) {
    return (unsigned)(unsigned short)f2bf(a) | ((unsigned)(unsigned short)f2bf(b) << 16);
}
__device__ __forceinline__ float bf2f(short s) {
    union { unsigned u; float f; } v; v.u = ((unsigned)(unsigned short)s) << 16;
    return v.f;
}
__device__ __forceinline__ bf16x8 ld_frag4(const short* p) {   // 4B-aligned LDS frag load
    bf16x8u v = *(const bf16x8u*)p;
    return (bf16x8)v;
}

// ---------------------------------------------------------------------------
// Kernel 0: punish matrix -> bf16 [T][TPAD], zero pad cols.
// ---------------------------------------------------------------------------
__global__ __launch_bounds__(256) void convp2_kernel(
    const float* __restrict__ P, short* __restrict__ Pbf)
{
    const int g = blockIdx.x * 256 + threadIdx.x;
    const int NG4 = TPAD / 4;                       // 416
    if (g >= TT * NG4) return;
    const int r = g / NG4, c4 = (g - r * NG4) * 4;
    float p0 = 0.f, p1 = 0.f, p2 = 0.f, p3 = 0.f;
    const float* prow = P + (size_t)r * TT;
    if (c4 + 0 < TT) p0 = prow[c4 + 0];
    if (c4 + 1 < TT) p1 = prow[c4 + 1];
    if (c4 + 2 < TT) p2 = prow[c4 + 2];
    if (c4 + 3 < TT) p3 = prow[c4 + 3];
    uint2 o; o.x = pack2(p0, p1); o.y = pack2(p2, p3);
    *(uint2*)(Pbf + (size_t)r * TPAD + c4) = o;
}

// ---------------------------------------------------------------------------
// Kernel 1 (MFMA): projections Q/K/V in [B, D, T] scramble layout, bf16 out.
//   Y[b,d,t] = sum_k W[d,k] X[b,t,k] (+bias, sigmoid for Q/K)
// Both operands are k-contiguous in global -> no transpose staging needed.
// ---------------------------------------------------------------------------
__global__ __launch_bounds__(256) void proj2_kernel(
    const float* __restrict__ X,
    const float* __restrict__ W0, const float* __restrict__ b0,
    const float* __restrict__ W1, const float* __restrict__ b1,
    const float* __restrict__ W2, const float* __restrict__ b2,
    short* __restrict__ Y0, short* __restrict__ Y1, short* __restrict__ Y2)
{
    __shared__ short Wsh[64][72];  // [d][k] bf16
    __shared__ short Xs[64][72];   // [t][k] bf16

    const int tt = blockIdx.x, dt = blockIdx.y, z = blockIdx.z;
    const int b = z / 3, which = z % 3;
    const float* W    = (which == 0) ? W0 : (which == 1) ? W1 : W2;
    const float* bias = (which == 0) ? b0 : (which == 1) ? b1 : b2;
    short* Y          = (which == 0) ? Y0 : (which == 1) ? Y1 : Y2;

    const int t0 = tt * 64, d0 = dt * 64;
    const float* Xb = X + (size_t)b * TT * DD;

    const int tid  = threadIdx.x;
    const int wave = tid >> 6, lane = tid & 63;
    const int quad = lane >> 4, l16 = lane & 15;
    const int srow = tid >> 2, scg = (tid & 3) * 16;

    f32x4 acc[4];
    #pragma unroll
    for (int i = 0; i < 4; ++i) acc[i] = (f32x4){0.f, 0.f, 0.f, 0.f};

    for (int k0 = 0; k0 < DD; k0 += 64) {
        // stage W row (d0+srow) and X row (t0+srow), k-cols [k0+scg, +16)
        {
            const float* wrow = W + (size_t)(d0 + srow) * DD + k0 + scg;
            float4 w0 = *(const float4*)(wrow);
            float4 w1 = *(const float4*)(wrow + 4);
            float4 w2 = *(const float4*)(wrow + 8);
            float4 w3 = *(const float4*)(wrow + 12);
            uint4 pw0, pw1;
            pw0.x = pack2(w0.x, w0.y); pw0.y = pack2(w0.z, w0.w);
            pw0.z = pack2(w1.x, w1.y); pw0.w = pack2(w1.z, w1.w);
            pw1.x = pack2(w2.x, w2.y); pw1.y = pack2(w2.z, w2.w);
            pw1.z = pack2(w3.x, w3.y); pw1.w = pack2(w3.z, w3.w);

            const int t = t0 + srow;
            float4 x0 = make_float4(0.f,0.f,0.f,0.f), x1 = x0, x2 = x0, x3 = x0;
            if (t < TT) {
                const float* xrow = Xb + (size_t)t * DD + k0 + scg;
                x0 = *(const float4*)(xrow);
                x1 = *(const float4*)(xrow + 4);
                x2 = *(const float4*)(xrow + 8);
                x3 = *(const float4*)(xrow + 12);
            }
            uint4 px0, px1;
            px0.x = pack2(x0.x, x0.y); px0.y = pack2(x0.z, x0.w);
            px0.z = pack2(x1.x, x1.y); px0.w = pack2(x1.z, x1.w);
            px1.x = pack2(x2.x, x2.y); px1.y = pack2(x2.z, x2.w);
            px1.z = pack2(x3.x, x3.y); px1.w = pack2(x3.z, x3.w);

            __syncthreads();
            *(uint4*)&Wsh[srow][scg]     = pw0;
            *(uint4*)&Wsh[srow][scg + 8] = pw1;
            *(uint4*)&Xs[srow][scg]      = px0;
            *(uint4*)&Xs[srow][scg + 8]  = px1;
        }
        __syncthreads();

        #pragma unroll
        for (int ks = 0; ks < 2; ++ks) {
            bf16x8 a = *(const bf16x8*)&Wsh[wave * 16 + l16][ks * 32 + quad * 8];
            #pragma unroll
            for (int nt = 0; nt < 4; ++nt) {
                bf16x8 bb = *(const bf16x8*)&Xs[nt * 16 + l16][ks * 32 + quad * 8];
                acc[nt] = __builtin_amdgcn_mfma_f32_16x16x32_bf16(a, bb, acc[nt], 0, 0, 0);
            }
        }
    }

    // epilogue: C row (quad*4+r) = d, col (l16) = t
    #pragma unroll
    for (int nt = 0; nt < 4; ++nt) {
        const int t = t0 + nt * 16 + l16;
        if (t < TT) {
            #pragma unroll
            for (int r = 0; r < 4; ++r) {
                const int d = d0 + wave * 16 + quad * 4 + r;
                float v = acc[nt][r] + bias[d];
                if (which < 2) v = 1.2f / (1.0f + __expf(-1.6f * v));
                Y[((size_t)b * DD + d) * TT + t] = f2bf(v);
            }
        }
    }
}

// ---------------------------------------------------------------------------
// Kernel 2 (MFMA): partial Mt.
//   Mpart[jc][be][d][s] = sum_{j in chunk jc} V[j][d] * O[j][s]
// Dense 256B global requests (consecutive lanes -> consecutive dwords).
// LDS row stride 66 shorts (33 dwords): lane stride 33 = 1 mod 32 ->
// conflict-free transpose writes. 25 KB LDS. Grid (13,16,4) = 832 blocks.
// ---------------------------------------------------------------------------
__global__ __launch_bounds__(256) void ovt3_kernel(
    const float* __restrict__ orth, const short* __restrict__ Vb,
    float* __restrict__ Mpart)
{
    __shared__ short Os[STILE][66];  // [s_local][j_local] bf16
    __shared__ short Vs[64][66];     // [d][j_local] bf16

    const int sq = blockIdx.x, be = blockIdx.y, jc = blockIdx.z;
    const int s0 = sq * STILE;
    const int jt0 = (jc < 2) ? jc * 7 : 14 + (jc - 2) * 6;   // tiles {7,7,6,6}
    const int jtn = (jc < 2) ? 7 : 6;

    const float* O  = orth + (size_t)be * TT * TT;
    const short* Vh = Vb + (size_t)be * DE * TT;   // head block read as [j][64]

    const int tid  = threadIdx.x;
    const int wave = tid >> 6, lane = tid & 63;
    const int quad = lane >> 4, l16 = lane & 15;

    f32x4 acc[4][2];   // [d-strip][s-strip]
    #pragma unroll
    for (int i = 0; i < 4; ++i)
        #pragma unroll
        for (int j = 0; j < 2; ++j) acc[i][j] = (f32x4){0.f, 0.f, 0.f, 0.f};

    for (int t = 0; t < jtn; ++t) {
        const int j0 = (jt0 + t) * 64;

        #pragma unroll
        for (int u = 0; u < 8; ++u) {
            const int jl = wave * 16 + 2 * u;
            const int j  = j0 + jl;

            float o0[2] = {0.f, 0.f}, o1[2] = {0.f, 0.f};
            #pragma unroll
            for (int i = 0; i < 2; ++i) {
                const int c = s0 + lane + 64 * i;
                if (c < TT) {
                    if (j < TT)     o0[i] = O[(size_t)j * TT + c];
                    if (j + 1 < TT) o1[i] = O[(size_t)(j + 1) * TT + c];
                }
            }
            #pragma unroll
            for (int i = 0; i < 2; ++i)
                *(unsigned*)&Os[lane + 64 * i][jl] = pack2(o0[i], o1[i]);

            short v0 = 0, v1 = 0;
            if (j < TT)     v0 = Vh[(size_t)j * DE + lane];
            if (j + 1 < TT) v1 = Vh[(size_t)(j + 1) * DE + lane];
            *(unsigned*)&Vs[lane][jl] =
                (unsigned)(unsigned short)v0 | ((unsigned)(unsigned short)v1 << 16);
        }
        __syncthreads();

        // wave owns all 64 d x s-strip [wave*32, wave*32+32)
        #pragma unroll
        for (int ks = 0; ks < 2; ++ks) {
            bf16x8 a[4], bb[2];
            #pragma unroll
            for (int i = 0; i < 4; ++i)
                a[i] = ld_frag4(&Vs[i * 16 + l16][ks * 32 + quad * 8]);
            #pragma unroll
            for (int jj = 0; jj < 2; ++jj)
                bb[jj] = ld_frag4(&Os[wave * 32 + jj * 16 + l16][ks * 32 + quad * 8]);
            #pragma unroll
            for (int i = 0; i < 4; ++i)
                #pragma unroll
                for (int jj = 0; jj < 2; ++jj)
                    acc[i][jj] = __builtin_amdgcn_mfma_f32_16x16x32_bf16(a[i], bb[jj], acc[i][jj], 0, 0, 0);
        }
        __syncthreads();
    }

    // epilogue: fp32 partial write. d = i*16+quad*4+r, s = s0+wave*32+jj*16+l16
    float* Mp = Mpart + (size_t)(jc * BEH + be) * DE * MPSTRIDE;
    #pragma unroll
    for (int i = 0; i < 4; ++i) {
        #pragma unroll
        for (int jj = 0; jj < 2; ++jj) {
            const int s = s0 + wave * 32 + jj * 16 + l16;
            #pragma unroll
            for (int r = 0; r < 4; ++r) {
                const int d = i * 16 + quad * 4 + r;
                Mp[(size_t)d * MPSTRIDE + s] = acc[i][jj][r];
            }
        }
    }
}

// ---------------------------------------------------------------------------
// Kernel 2b: reduce the 4 j-chunk partials -> bf16 Mt[be][d][TPAD].
// ---------------------------------------------------------------------------
__global__ __launch_bounds__(256) void mreduce_kernel(
    const float* __restrict__ Mpart, short* __restrict__ Mt)
{
    const int g = blockIdx.x * 256 + threadIdx.x;
    const int NG = TPAD / 4;                        // 416
    if (g >= BEH * DE * NG) return;
    const int bd = g / NG;
    const int s4 = (g - bd * NG) * 4;

    const size_t jstride = (size_t)BEH * DE * MPSTRIDE;
    const float* p = Mpart + (size_t)bd * MPSTRIDE + s4;
    float4 a0 = *(const float4*)(p);
    float4 a1 = *(const float4*)(p + jstride);
    float4 a2 = *(const float4*)(p + 2 * jstride);
    float4 a3 = *(const float4*)(p + 3 * jstride);
    float s0 = a0.x + a1.x + a2.x + a3.x;
    float s1 = a0.y + a1.y + a2.y + a3.y;
    float s2 = a0.z + a1.z + a2.z + a3.z;
    float s3 = a0.w + a1.w + a2.w + a3.w;

    uint2 o;
    o.x = pack2(s0, s1);
    o.y = pack2(s2, s3);
    *(uint2*)(Mt + (size_t)bd * TPAD + s4) = o;
}

// ---------------------------------------------------------------------------
// Kernel 3 (MFMA): fused attention, P in bf16 (exact shift to fp32 on use).
// LDS = 5 x 9216 = 46 KB -> 3 blocks/CU.
// ---------------------------------------------------------------------------
__global__ __launch_bounds__(256) void attn2_kernel(
    const short* __restrict__ Qb, const short* __restrict__ Kb,
    const short* __restrict__ Mt, const short* __restrict__ Pbf,
    float* __restrict__ Hbuf)
{
    __shared__ short Qs[64][72];  // [i][d]
    __shared__ short Ks[64][72];  // [s][d]
    __shared__ short Ms[64][72];  // [d][s]
    __shared__ short Wl[64][72];  // [i][s]
    __shared__ short Ps[64][72];  // [i][s] bf16 punish tile

    const int it = blockIdx.x, be = blockIdx.y;
    const int b = be >> 3, e = be & 7;
    const int i0 = it * 64;
    const short* Qh = Qb + (size_t)be * DE * TT;
    const short* Kh = Kb + (size_t)be * DE * TT;
    const short* Mh = Mt + (size_t)be * DE * TPAD;

    const int tid  = threadIdx.x;
    const int wave = tid >> 6, lane = tid & 63;
    const int quad = lane >> 4, l16 = lane & 15;

    const float invs = 0.024598297f;  // 1/sqrt(1653)

    const int srow = tid >> 2, scg = (tid & 3) * 16;

    {
        const int gi = i0 + srow;
        uint4 z = make_uint4(0u, 0u, 0u, 0u);
        uint4 v0 = z, v1 = z;
        if (gi < TT) {
            v0 = *(const uint4*)(Qh + (size_t)gi * DE + scg);
            v1 = *(const uint4*)(Qh + (size_t)gi * DE + scg + 8);
        }
        *(uint4*)&Qs[srow][scg]     = v0;
        *(uint4*)&Qs[srow][scg + 8] = v1;
    }

    f32x4 out[4];
    #pragma unroll
    for (int i = 0; i < 4; ++i) out[i] = (f32x4){0.f, 0.f, 0.f, 0.f};

    for (int s0 = 0; s0 < TT; s0 += 64) {
        {
            const int gs = s0 + srow;
            uint4 z = make_uint4(0u, 0u, 0u, 0u);
            uint4 k0 = z, k1 = z;
            if (gs < TT) {
                k0 = *(const uint4*)(Kh + (size_t)gs * DE + scg);
                k1 = *(const uint4*)(Kh + (size_t)gs * DE + scg + 8);
            }
            *(uint4*)&Ks[srow][scg]     = k0;
            *(uint4*)&Ks[srow][scg + 8] = k1;

            uint4 m0 = *(const uint4*)(Mh + (size_t)srow * TPAD + s0 + scg);
            uint4 m1 = *(const uint4*)(Mh + (size_t)srow * TPAD + s0 + scg + 8);
            *(uint4*)&Ms[srow][scg]     = m0;
            *(uint4*)&Ms[srow][scg + 8] = m1;

            const int gi = i0 + srow;
            uint4 p0 = z, p1 = z;
            if (gi < TT) {
                p0 = *(const uint4*)(Pbf + (size_t)gi * TPAD + s0 + scg);
                p1 = *(const uint4*)(Pbf + (size_t)gi * TPAD + s0 + scg + 8);
            }
            *(uint4*)&Ps[srow][scg]     = p0;
            *(uint4*)&Ps[srow][scg + 8] = p1;
        }
        __syncthreads();

        f32x4 w[4];
        #pragma unroll
        for (int i = 0; i < 4; ++i) w[i] = (f32x4){0.f, 0.f, 0.f, 0.f};
        #pragma unroll
        for (int ks = 0; ks < 2; ++ks) {
            bf16x8 a = *(const bf16x8*)&Qs[wave * 16 + l16][ks * 32 + quad * 8];
            #pragma unroll
            for (int stile = 0; stile < 4; ++stile) {
                bf16x8 bb = *(const bf16x8*)&Ks[stile * 16 + l16][ks * 32 + quad * 8];
                w[stile] = __builtin_amdgcn_mfma_f32_16x16x32_bf16(a, bb, w[stile], 0, 0, 0);
            }
        }

        #pragma unroll
        for (int stile = 0; stile < 4; ++stile) {
            const int sl = stile * 16 + l16;
            #pragma unroll
            for (int r = 0; r < 4; ++r) {
                const int il = wave * 16 + quad * 4 + r;
                float v = w[stile][r] * invs * bf2f(Ps[il][sl]);
                Wl[il][sl] = f2bf(v);
            }
        }

        #pragma unroll
        for (int ks = 0; ks < 2; ++ks) {
            bf16x8 a = *(const bf16x8*)&Wl[wave * 16 + l16][ks * 32 + quad * 8];
            #pragma unroll
            for (int dt = 0; dt < 4; ++dt) {
                bf16x8 bb = *(const bf16x8*)&Ms[dt * 16 + l16][ks * 32 + quad * 8];
                out[dt] = __builtin_amdgcn_mfma_f32_16x16x32_bf16(a, bb, out[dt], 0, 0, 0);
            }
        }
        __syncthreads();
    }

    #pragma unroll
    for (int dt = 0; dt < 4; ++dt) {
        const int d = dt * 16 + l16;
        #pragma unroll
        for (int r = 0; r < 4; ++r) {
            const int gi = i0 + wave * 16 + quad * 4 + r;
            if (gi < TT)
                Hbuf[((size_t)b * TT + gi) * DD + e * 64 + d] = out[dt][r];
        }
    }
}

// ---------------------------------------------------------------------------
// Kernel 4: final projection (fp32 SGEMM, precision anchor for the output).
// ---------------------------------------------------------------------------
__global__ __launch_bounds__(256) void oproj_kernel(
    const float* __restrict__ H, const float* __restrict__ Wo,
    const float* __restrict__ bo, float* __restrict__ out)
{
    __shared__ float Hs[16][68];
    __shared__ float Ns[16][68];

    const int tt = blockIdx.x, nt = blockIdx.y, b = blockIdx.z;
    const int t0 = tt * 64, n0 = nt * 64;
    const float* Hb = H + (size_t)b * TT * DD;

    const int tid = threadIdx.x;
    const int tx = tid & 15, ty = tid >> 4;
    const int lrow = tid >> 2, lq = tid & 3;
    const int trow = t0 + lrow;

    float acc[4][4] = {};

    for (int k0 = 0; k0 < DD; k0 += 16) {
        float4 hv = make_float4(0.f, 0.f, 0.f, 0.f);
        if (trow < TT)
            hv = *(const float4*)(Hb + (size_t)trow * DD + k0 + lq*4);
        float4 wv = *(const float4*)(Wo + (size_t)(n0 + lrow) * DD + k0 + lq*4);
        __syncthreads();
        Hs[lq*4+0][lrow] = hv.x; Hs[lq*4+1][lrow] = hv.y;
        Hs[lq*4+2][lrow] = hv.z; Hs[lq*4+3][lrow] = hv.w;
        Ns[lq*4+0][lrow] = wv.x; Ns[lq*4+1][lrow] = wv.y;
        Ns[lq*4+2][lrow] = wv.z; Ns[lq*4+3][lrow] = wv.w;
        __syncthreads();
        #pragma unroll
        for (int k = 0; k < 16; ++k) {
            float4 a4 = *(const float4*)(&Hs[k][ty*4]);
            float4 c4 = *(const float4*)(&Ns[k][tx*4]);
            float a[4] = {a4.x, a4.y, a4.z, a4.w};
            float c[4] = {c4.x, c4.y, c4.z, c4.w};
            #pragma unroll
            for (int i = 0; i < 4; ++i)
                #pragma unroll
                for (int j = 0; j < 4; ++j)
                    acc[i][j] = fmaf(a[i], c[j], acc[i][j]);
        }
        __syncthreads();
    }

    #pragma unroll
    for (int i = 0; i < 4; ++i) {
        const int t = t0 + ty*4 + i;
        if (t < TT) {
            float4 v;
            v.x = acc[i][0] + bo[n0 + tx*4 + 0];
            v.y = acc[i][1] + bo[n0 + tx*4 + 1];
            v.z = acc[i][2] + bo[n0 + tx*4 + 2];
            v.w = acc[i][3] + bo[n0 + tx*4 + 3];
            *(float4*)(out + ((size_t)b * TT + t) * DD + n0 + tx*4) = v;
        }
    }
}

// ---------------------------------------------------------------------------
extern "C" void kernel_launch(void* const* d_in, const int* in_sizes, int n_in,
                              void* d_out, int out_size, void* d_ws, size_t ws_size,
                              hipStream_t stream)
{
    (void)in_sizes; (void)n_in; (void)out_size; (void)ws_size;

    const float* X    = (const float*)d_in[0];
    const float* Wq   = (const float*)d_in[1];
    const float* bq   = (const float*)d_in[2];
    const float* Wk   = (const float*)d_in[3];
    const float* bk   = (const float*)d_in[4];
    const float* Wv   = (const float*)d_in[5];
    const float* bv   = (const float*)d_in[6];
    const float* Wo   = (const float*)d_in[7];
    const float* bo   = (const float*)d_in[8];
    const float* P    = (const float*)d_in[9];
    const float* orth = (const float*)d_in[10];
    float* out = (float*)d_out;

    // Workspace layout (~46.3 MB):
    //   Qb/Kb/Vb bf16 [B*D*T]        3 x 3,385,344 B
    //   Mtb      bf16 [BE*64*TPAD]       3,407,872 B
    //   Pbf      bf16 [T*TPAD]           5,501,184 B
    //   Mpart    fp32 [4][BE*64][TPAD]  27,262,976 B  (dead after mreduce)
    //   Hbuf     fp32 [B*T*D] -- ALIASES Mpart (written by attn after mreduce)
    char* ws = (char*)d_ws;
    const size_t SZH = (size_t)BB * DD * TT * sizeof(short);
    short* Qb  = (short*)(ws);
    short* Kb  = (short*)(ws + SZH);
    short* Vb  = (short*)(ws + 2 * SZH);
    short* Mtb = (short*)(ws + 3 * SZH);
    short* Pbf = (short*)(ws + 3 * SZH + (size_t)BEH * DE * TPAD * sizeof(short));
    char*  after_p = ws + 3 * SZH + (size_t)BEH * DE * TPAD * sizeof(short)
                        + (size_t)TT * TPAD * sizeof(short);
    float* Mpart = (float*)after_p;
    float* Hbuf  = (float*)after_p;   // alias: Mpart dead before attn runs

    dim3 blk(256);

    convp2_kernel<<<dim3((TT * (TPAD / 4) + 255) / 256), blk, 0, stream>>>(P, Pbf);

    dim3 g1(TTILES, DD / 64, BB * 3);
    proj2_kernel<<<g1, blk, 0, stream>>>(X, Wq, bq, Wk, bk, Wv, bv, Qb, Kb, Vb);

    dim3 g2(SQN, BEH, NJC);
    ovt3_kernel<<<g2, blk, 0, stream>>>(orth, Vb, Mpart);

    dim3 gr((BEH * DE * (TPAD / 4) + 255) / 256);
    mreduce_kernel<<<gr, blk, 0, stream>>>(Mpart, Mtb);

    dim3 g3(TTILES, BEH);
    attn2_kernel<<<g3, blk, 0, stream>>>(Qb, Kb, Mtb, Pbf, Hbuf);

    dim3 g4(TTILES, DD / 64, BB);
    oproj_kernel<<<g4, blk, 0, stream>>>(Hbuf, Wo, bo, out);
}